// Round 5
// baseline (60.931 us; speedup 1.0000x reference)
//
#include <hip/hip_runtime.h>
#include <hip/hip_bf16.h>

// GAT layer: out[b,i,j] = lrelu( (h@W@a1)[b,i] + (h@W@a2)[b,j] )
// B=4, N=4096, IN_F=256, OUT_F=64. Output: 4*4096*4096 fp32 = 256 MiB (write-bound).
// Algebraic collapse: e1 = h@(W@a1), e2 = h@(W@a2) — Wh never materialized.

#define B_DIM 4
#define N_DIM 4096
#define IN_F 256
#define OUT_F 64
#define SLOPE 0.2f

typedef float f32x4 __attribute__((ext_vector_type(4)));

// K1: fused v + dots. 1024 blocks x 256 threads (16 rows of h per block).
// Phase 1 (wave-cooperative, coalesced): wave w computes v1/v2 for rows
// [w*64, w*64+64). Lanes = 4 rows x 16 chunks; each iteration reads 1 KB of W
// contiguously (16 chunks x 4 rows), f32x4 dot vs a-chunk, then 4-level
// shfl_xor reduce within each 16-lane chunk group. 16 iterations total.
// Phase 2: wave-per-row dots of h rows vs v1/v2 (4 rows per wave).
__global__ __launch_bounds__(256) void gat_dots(
        const float* __restrict__ h, const float* __restrict__ W,
        const float* __restrict__ a,
        float* __restrict__ e1, float* __restrict__ e2) {
    __shared__ float v1s[IN_F];
    __shared__ float v2s[IN_F];
    const int t    = threadIdx.x;
    const int lane = t & 63;
    const int wid  = t >> 6;

    // ---- phase 1: v = W @ a (coalesced) ----
    {
        const int rgrp = lane >> 4;   // row within quad: 0..3
        const int ch   = lane & 15;   // 16-byte chunk: 0..15
        const f32x4 a1c = reinterpret_cast<const f32x4*>(a)[ch];
        const f32x4 a2c = reinterpret_cast<const f32x4*>(a + OUT_F)[ch];
        #pragma unroll
        for (int it = 0; it < 16; ++it) {
            const int row = wid * 64 + it * 4 + rgrp;
            const f32x4 wv = *reinterpret_cast<const f32x4*>(W + row * OUT_F + ch * 4);
            float s1 = wv.x * a1c.x + wv.y * a1c.y + wv.z * a1c.z + wv.w * a1c.w;
            float s2 = wv.x * a2c.x + wv.y * a2c.y + wv.z * a2c.z + wv.w * a2c.w;
            #pragma unroll
            for (int m = 8; m >= 1; m >>= 1) {   // reduce over the 16 chunk lanes
                s1 += __shfl_xor(s1, m);
                s2 += __shfl_xor(s2, m);
            }
            if (ch == 0) {
                v1s[row] = s1;
                v2s[row] = s2;
            }
        }
    }
    __syncthreads();

    // ---- phase 2: e1/e2 row dots (wave per row, 4 rows per wave) ----
    const f32x4 v1 = reinterpret_cast<const f32x4*>(v1s)[lane];
    const f32x4 v2 = reinterpret_cast<const f32x4*>(v2s)[lane];
    const int base = blockIdx.x * 16 + wid * 4;

    #pragma unroll
    for (int r = 0; r < 4; ++r) {
        const int row = base + r;
        const f32x4 hv = reinterpret_cast<const f32x4*>(h + (size_t)row * IN_F)[lane];
        float d1 = hv.x * v1.x + hv.y * v1.y + hv.z * v1.z + hv.w * v1.w;
        float d2 = hv.x * v2.x + hv.y * v2.y + hv.z * v2.z + hv.w * v2.w;
        #pragma unroll
        for (int m = 32; m >= 1; m >>= 1) {
            d1 += __shfl_xor(d1, m);
            d2 += __shfl_xor(d2, m);
        }
        if (lane == 0) {
            e1[row] = d1;
            e2[row] = d2;
        }
    }
}

// K2: epilogue. 2048 blocks x 256 threads, 8 rows per block. e2 chunk in 16
// registers (loaded once), e1[8] prefetched into registers -> the store loop
// is 32 back-to-back dwordx4 stores with no dependent loads.
__global__ __launch_bounds__(256) void gat_epilogue(
        const float* __restrict__ e1, const float* __restrict__ e2,
        float* __restrict__ out) {
    const int rowBase = blockIdx.x * 8;        // b*N + i base
    const int b       = rowBase >> 12;
    const int tid     = threadIdx.x;

    const f32x4* e2v = reinterpret_cast<const f32x4*>(e2 + b * N_DIM);
    const f32x4 c0 = e2v[tid];
    const f32x4 c1 = e2v[tid + 256];
    const f32x4 c2 = e2v[tid + 512];
    const f32x4 c3 = e2v[tid + 768];

    float s[8];
    #pragma unroll
    for (int r = 0; r < 8; ++r) s[r] = e1[rowBase + r];   // uniform -> scalar loads

    #pragma unroll
    for (int r = 0; r < 8; ++r) {
        f32x4* outv = reinterpret_cast<f32x4*>(out + (size_t)(rowBase + r) * N_DIM);
        f32x4 o0, o1, o2, o3;
        #define LRELU(dst, src) { \
            float ex = s[r] + (src).x; (dst).x = fmaxf(ex, SLOPE * ex); \
            float ey = s[r] + (src).y; (dst).y = fmaxf(ey, SLOPE * ey); \
            float ez = s[r] + (src).z; (dst).z = fmaxf(ez, SLOPE * ez); \
            float ew = s[r] + (src).w; (dst).w = fmaxf(ew, SLOPE * ew); }
        LRELU(o0, c0) LRELU(o1, c1) LRELU(o2, c2) LRELU(o3, c3)
        #undef LRELU
        outv[tid]       = o0;
        outv[tid + 256] = o1;
        outv[tid + 512] = o2;
        outv[tid + 768] = o3;
    }
}

extern "C" void kernel_launch(void* const* d_in, const int* in_sizes, int n_in,
                              void* d_out, int out_size, void* d_ws, size_t ws_size,
                              hipStream_t stream) {
    const float* h = (const float*)d_in[0];   // 4*4096*256
    const float* W = (const float*)d_in[1];   // 256*64
    const float* a = (const float*)d_in[2];   // 128

    float* ws = (float*)d_ws;
    float* e1 = ws;                    // 16384 floats
    float* e2 = ws + 16384;            // 16384 floats

    gat_dots<<<1024, 256, 0, stream>>>(h, W, a, e1, e2);
    gat_epilogue<<<2048, 256, 0, stream>>>(e1, e2, (float*)d_out);
}